// Round 2
// baseline (528.606 us; speedup 1.0000x reference)
//
#include <hip/hip_runtime.h>

// out[i] = z[i] - COEFF * (2/N) * nf[i] * g[i]
// g[i]   = deg(i) * zr[i] - sum_{j in adj(i)} zr[j],   zr[j] = nf[j]*z[j]
// adj(i) counts both edge directions (row->col and col->row).
//
// Pipeline (all in d_ws):
//   1) hist: deg[node]++ over 2E incidences           (int atomics)
//   2) exclusive scan deg -> starts  (3 small kernels)
//   3) scatter: adj[starts[node] + bump[node]++] = other
//   4) gather+finalize: wave per node, lane = feature dim

#define SCAN_CHUNK 2048  // 256 threads * 8 elements

__global__ void hist_kernel(const int* __restrict__ ei, int* __restrict__ deg, int twoE) {
    int t = blockIdx.x * blockDim.x + threadIdx.x;
    int stride = gridDim.x * blockDim.x;
    for (; t < twoE; t += stride) atomicAdd(&deg[ei[t]], 1);
}

__global__ __launch_bounds__(256) void scan_block_sums(const int* __restrict__ deg,
                                                       int* __restrict__ bsum, int N) {
    __shared__ int lds[256];
    int base = blockIdx.x * SCAN_CHUNK;
    int s = 0;
    #pragma unroll
    for (int k = 0; k < 8; ++k) {
        int i = base + k * 256 + threadIdx.x;
        if (i < N) s += deg[i];
    }
    lds[threadIdx.x] = s;
    __syncthreads();
    for (int off = 128; off > 0; off >>= 1) {
        if (threadIdx.x < off) lds[threadIdx.x] += lds[threadIdx.x + off];
        __syncthreads();
    }
    if (threadIdx.x == 0) bsum[blockIdx.x] = lds[0];
}

__global__ void scan_bsums(const int* __restrict__ bsum, int* __restrict__ boff, int NB) {
    __shared__ int lds[1024];
    for (int i = threadIdx.x; i < 1024; i += blockDim.x) lds[i] = (i < NB) ? bsum[i] : 0;
    __syncthreads();
    if (threadIdx.x == 0) {
        int run = 0;
        for (int i = 0; i < NB; ++i) { int v = lds[i]; lds[i] = run; run += v; }
    }
    __syncthreads();
    for (int i = threadIdx.x; i < NB; i += blockDim.x) boff[i] = lds[i];
}

__global__ __launch_bounds__(256) void scan_chunks(const int* __restrict__ deg,
                                                   const int* __restrict__ boff,
                                                   int* __restrict__ starts, int N) {
    __shared__ int buf[SCAN_CHUNK];
    __shared__ int tsum[256];
    int base = blockIdx.x * SCAN_CHUNK;
    #pragma unroll
    for (int k = 0; k < 8; ++k) {
        int i = base + k * 256 + threadIdx.x;
        buf[k * 256 + threadIdx.x] = (i < N) ? deg[i] : 0;
    }
    __syncthreads();
    int lo = threadIdx.x * 8;
    int s = 0;
    #pragma unroll
    for (int k = 0; k < 8; ++k) s += buf[lo + k];
    tsum[threadIdx.x] = s;
    __syncthreads();
    for (int off = 1; off < 256; off <<= 1) {
        int a = tsum[threadIdx.x];
        int b = (threadIdx.x >= (unsigned)off) ? tsum[threadIdx.x - off] : 0;
        __syncthreads();
        tsum[threadIdx.x] = a + b;
        __syncthreads();
    }
    int run = boff[blockIdx.x] + (tsum[threadIdx.x] - s);  // exclusive thread prefix
    #pragma unroll
    for (int k = 0; k < 8; ++k) {
        int i = base + lo + k;
        if (i < N) starts[i] = run;
        run += buf[lo + k];
    }
}

__global__ void scatter_kernel(const int* __restrict__ ei, const int* __restrict__ starts,
                               int* __restrict__ bump, int* __restrict__ adj, int E) {
    int t = blockIdx.x * blockDim.x + threadIdx.x;
    int stride = gridDim.x * blockDim.x;
    int twoE = 2 * E;
    for (; t < twoE; t += stride) {
        int node = ei[t];
        int other = (t < E) ? ei[t + E] : ei[t - E];
        int pos = starts[node] + atomicAdd(&bump[node], 1);
        adj[pos] = other;
    }
}

__global__ __launch_bounds__(256) void gather_finalize_kernel(
        const float* __restrict__ z, const float* __restrict__ nf,
        const int* __restrict__ starts, const int* __restrict__ deg,
        const int* __restrict__ adj, float* __restrict__ out,
        float scale, int N, int D) {
    int wid  = threadIdx.x >> 6;
    int lane = threadIdx.x & 63;
    int node = blockIdx.x * 4 + wid;
    if (node >= N) return;
    int s  = starts[node];
    int dg = deg[node];
    float sum = 0.f;
    for (int base = 0; base < dg; base += 64) {
        int rem = dg - base;
        int cnt = rem < 64 ? rem : 64;
        int   jreg  = (lane < cnt) ? adj[s + base + lane] : 0;
        float nfreg = (lane < cnt) ? nf[jreg] : 0.f;
        #pragma unroll 4
        for (int k = 0; k < cnt; ++k) {
            int   j   = __shfl(jreg, k, 64);
            float nfj = __shfl(nfreg, k, 64);
            float v   = (lane < D) ? z[j * D + lane] : 0.f;
            sum += nfj * v;
        }
    }
    if (lane < D) {
        int idx   = node * D + lane;
        float zi  = z[idx];
        float nfi = nf[node];
        float g   = (float)dg * (nfi * zi) - sum;
        out[idx]  = zi - scale * nfi * g;
    }
}

// ---- fallback (round-1 atomic path) if ws too small ----
__global__ void edge_scatter_kernel(const float* __restrict__ z, const int* __restrict__ ei,
                                    const float* __restrict__ nf, float* __restrict__ acc,
                                    int E, int D, long total) {
    long idx = (long)blockIdx.x * blockDim.x + threadIdx.x;
    if (idx >= total) return;
    int e = (int)(idx / D);
    int d = (int)(idx - (long)e * D);
    int r = ei[e];
    int c = ei[E + e];
    float diff = nf[r] * z[(long)r * D + d] - nf[c] * z[(long)c * D + d];
    atomicAdd(&acc[(long)r * D + d],  diff);
    atomicAdd(&acc[(long)c * D + d], -diff);
}
__global__ void finalize_kernel(const float* __restrict__ z, const float* __restrict__ nf,
                                float* __restrict__ out, float scale, int D, long total) {
    long i = (long)blockIdx.x * blockDim.x + threadIdx.x;
    if (i >= total) return;
    int node = (int)(i / D);
    out[i] = z[i] - scale * nf[node] * out[i];
}

extern "C" void kernel_launch(void* const* d_in, const int* in_sizes, int n_in,
                              void* d_out, int out_size, void* d_ws, size_t ws_size,
                              hipStream_t stream) {
    const float* z  = (const float*)d_in[0];
    const int*   ei = (const int*)d_in[2];
    const float* nf = (const float*)d_in[3];
    float* out = (float*)d_out;

    const int ND = in_sizes[0];
    const int Nn = in_sizes[3];
    const int D  = ND / Nn;
    const int E  = in_sizes[2] / 2;
    const int twoE = 2 * E;
    const float scale = 0.1f * 2.0f / (float)Nn;

    const int NB = (Nn + SCAN_CHUNK - 1) / SCAN_CHUNK;

    auto align_up = [](size_t x) { return (x + 255) & ~(size_t)255; };
    size_t off_deg    = 0;
    size_t off_starts = off_deg    + align_up((size_t)Nn * 4);
    size_t off_bump   = off_starts + align_up((size_t)Nn * 4);
    size_t off_bsum   = off_bump   + align_up((size_t)Nn * 4);
    size_t off_boff   = off_bsum   + align_up((size_t)NB * 4);
    size_t off_adj    = off_boff   + align_up((size_t)NB * 4);
    size_t need       = off_adj    + align_up((size_t)twoE * 4);

    if (ws_size < need) {
        // fallback: atomic scatter path
        hipMemsetAsync(out, 0, (size_t)ND * sizeof(float), stream);
        const int block = 256;
        const long totalE = (long)E * D;
        edge_scatter_kernel<<<(int)((totalE + block - 1) / block), block, 0, stream>>>(
            z, ei, nf, out, E, D, totalE);
        finalize_kernel<<<(ND + block - 1) / block, block, 0, stream>>>(
            z, nf, out, scale, D, (long)ND);
        return;
    }

    char* w = (char*)d_ws;
    int* deg    = (int*)(w + off_deg);
    int* starts = (int*)(w + off_starts);
    int* bump   = (int*)(w + off_bump);
    int* bsum   = (int*)(w + off_bsum);
    int* boff   = (int*)(w + off_boff);
    int* adj    = (int*)(w + off_adj);

    hipMemsetAsync(deg,  0, (size_t)Nn * 4, stream);
    hipMemsetAsync(bump, 0, (size_t)Nn * 4, stream);

    const int block = 256;
    int gridE = (twoE + block - 1) / block;
    if (gridE > 2048) gridE = 2048;

    hist_kernel<<<gridE, block, 0, stream>>>(ei, deg, twoE);
    scan_block_sums<<<NB, 256, 0, stream>>>(deg, bsum, Nn);
    scan_bsums<<<1, 256, 0, stream>>>(bsum, boff, NB);
    scan_chunks<<<NB, 256, 0, stream>>>(deg, boff, starts, Nn);
    scatter_kernel<<<gridE, block, 0, stream>>>(ei, starts, bump, adj, E);

    int gridG = (Nn + 3) / 4;  // 4 waves (nodes) per 256-thread block
    gather_finalize_kernel<<<gridG, 256, 0, stream>>>(z, nf, starts, deg, adj, out, scale, Nn, D);
}

// Round 3
// 305.221 us; speedup vs baseline: 1.7319x; 1.7319x over previous
//
#include <hip/hip_runtime.h>

// out[i] = z[i] - COEFF * (2/N) * nf[i] * g[i]
// g[i]   = deg(i) * zr[i] - sum_{j in adj(i)} zr[j],   zr[j] = nf[j]*z[j]
// adj(i) counts both edge directions.
//
// Pipeline (d_ws): hist+rank (atomic returns rank) -> scan -> rank-scatter
// (no atomics) -> gather+finalize (thread per (node, float4-chunk)).

#define SCAN_CHUNK 2048  // 256 threads * 8 elements

__global__ void hist_rank_kernel(const int* __restrict__ ei, int* __restrict__ deg,
                                 int* __restrict__ rank, int twoE) {
    int t = blockIdx.x * blockDim.x + threadIdx.x;
    if (t >= twoE) return;
    rank[t] = atomicAdd(&deg[ei[t]], 1);
}

__global__ __launch_bounds__(256) void scan_block_sums(const int* __restrict__ deg,
                                                       int* __restrict__ bsum, int N) {
    __shared__ int lds[256];
    int base = blockIdx.x * SCAN_CHUNK;
    int s = 0;
    #pragma unroll
    for (int k = 0; k < 8; ++k) {
        int i = base + k * 256 + threadIdx.x;
        if (i < N) s += deg[i];
    }
    lds[threadIdx.x] = s;
    __syncthreads();
    for (int off = 128; off > 0; off >>= 1) {
        if (threadIdx.x < off) lds[threadIdx.x] += lds[threadIdx.x + off];
        __syncthreads();
    }
    if (threadIdx.x == 0) bsum[blockIdx.x] = lds[0];
}

__global__ void scan_bsums(const int* __restrict__ bsum, int* __restrict__ boff, int NB) {
    __shared__ int lds[1024];
    for (int i = threadIdx.x; i < 1024; i += blockDim.x) lds[i] = (i < NB) ? bsum[i] : 0;
    __syncthreads();
    if (threadIdx.x == 0) {
        int run = 0;
        for (int i = 0; i < NB; ++i) { int v = lds[i]; lds[i] = run; run += v; }
    }
    __syncthreads();
    for (int i = threadIdx.x; i < NB; i += blockDim.x) boff[i] = lds[i];
}

__global__ __launch_bounds__(256) void scan_chunks(const int* __restrict__ deg,
                                                   const int* __restrict__ boff,
                                                   int* __restrict__ starts, int N) {
    __shared__ int buf[SCAN_CHUNK];
    __shared__ int tsum[256];
    int base = blockIdx.x * SCAN_CHUNK;
    #pragma unroll
    for (int k = 0; k < 8; ++k) {
        int i = base + k * 256 + threadIdx.x;
        buf[k * 256 + threadIdx.x] = (i < N) ? deg[i] : 0;
    }
    __syncthreads();
    int lo = threadIdx.x * 8;
    int s = 0;
    #pragma unroll
    for (int k = 0; k < 8; ++k) s += buf[lo + k];
    tsum[threadIdx.x] = s;
    __syncthreads();
    for (int off = 1; off < 256; off <<= 1) {
        int a = tsum[threadIdx.x];
        int b = (threadIdx.x >= (unsigned)off) ? tsum[threadIdx.x - off] : 0;
        __syncthreads();
        tsum[threadIdx.x] = a + b;
        __syncthreads();
    }
    int run = boff[blockIdx.x] + (tsum[threadIdx.x] - s);  // exclusive thread prefix
    #pragma unroll
    for (int k = 0; k < 8; ++k) {
        int i = base + lo + k;
        if (i < N) starts[i] = run;
        run += buf[lo + k];
    }
}

__global__ void scatter_rank_kernel(const int* __restrict__ ei, const int* __restrict__ starts,
                                    const int* __restrict__ rank, int* __restrict__ adj, int E) {
    int t = blockIdx.x * blockDim.x + threadIdx.x;
    int twoE = 2 * E;
    if (t >= twoE) return;
    int node  = ei[t];
    int other = (t < E) ? ei[t + E] : ei[t - E];
    adj[starts[node] + rank[t]] = other;
}

// bump-atomic scatter (mid fallback)
__global__ void scatter_bump_kernel(const int* __restrict__ ei, const int* __restrict__ starts,
                                    int* __restrict__ bump, int* __restrict__ adj, int E) {
    int t = blockIdx.x * blockDim.x + threadIdx.x;
    int twoE = 2 * E;
    if (t >= twoE) return;
    int node  = ei[t];
    int other = (t < E) ? ei[t + E] : ei[t - E];
    int pos = starts[node] + atomicAdd(&bump[node], 1);
    adj[pos] = other;
}

// Thread per (node, float4-chunk): 12 threads per node (D=48), fused finalize.
__global__ __launch_bounds__(256) void gather_finalize_v2(
        const float4* __restrict__ z4, const float* __restrict__ nf,
        const int* __restrict__ starts, const int* __restrict__ deg,
        const int* __restrict__ adj, float4* __restrict__ out4,
        float scale, int N, int C /* = D/4 */) {
    int t = blockIdx.x * blockDim.x + threadIdx.x;
    if (t >= N * C) return;
    int node = t / C;
    int c    = t - node * C;
    int s    = starts[node];
    int dg   = deg[node];
    float4 sum = make_float4(0.f, 0.f, 0.f, 0.f);
    #pragma unroll 4
    for (int k = 0; k < dg; ++k) {
        int   j   = adj[s + k];
        float nfj = nf[j];
        float4 v  = z4[(long)j * C + c];
        sum.x += nfj * v.x;
        sum.y += nfj * v.y;
        sum.z += nfj * v.z;
        sum.w += nfj * v.w;
    }
    float nfi = nf[node];
    float4 zi = z4[(long)node * C + c];
    float a   = scale * nfi;
    float dn  = (float)dg * nfi;
    float4 o;
    o.x = zi.x - a * (dn * zi.x - sum.x);
    o.y = zi.y - a * (dn * zi.y - sum.y);
    o.z = zi.z - a * (dn * zi.z - sum.z);
    o.w = zi.w - a * (dn * zi.w - sum.w);
    out4[t] = o;
}

// ---- low fallback (round-1 atomic path) ----
__global__ void edge_scatter_kernel(const float* __restrict__ z, const int* __restrict__ ei,
                                    const float* __restrict__ nf, float* __restrict__ acc,
                                    int E, int D, long total) {
    long idx = (long)blockIdx.x * blockDim.x + threadIdx.x;
    if (idx >= total) return;
    int e = (int)(idx / D);
    int d = (int)(idx - (long)e * D);
    int r = ei[e];
    int c = ei[E + e];
    float diff = nf[r] * z[(long)r * D + d] - nf[c] * z[(long)c * D + d];
    atomicAdd(&acc[(long)r * D + d],  diff);
    atomicAdd(&acc[(long)c * D + d], -diff);
}
__global__ void finalize_kernel(const float* __restrict__ z, const float* __restrict__ nf,
                                float* __restrict__ out, float scale, int D, long total) {
    long i = (long)blockIdx.x * blockDim.x + threadIdx.x;
    if (i >= total) return;
    int node = (int)(i / D);
    out[i] = z[i] - scale * nf[node] * out[i];
}

extern "C" void kernel_launch(void* const* d_in, const int* in_sizes, int n_in,
                              void* d_out, int out_size, void* d_ws, size_t ws_size,
                              hipStream_t stream) {
    const float* z  = (const float*)d_in[0];
    const int*   ei = (const int*)d_in[2];
    const float* nf = (const float*)d_in[3];
    float* out = (float*)d_out;

    const int ND = in_sizes[0];
    const int Nn = in_sizes[3];
    const int D  = ND / Nn;
    const int E  = in_sizes[2] / 2;
    const int twoE = 2 * E;
    const float scale = 0.1f * 2.0f / (float)Nn;

    const int NB = (Nn + SCAN_CHUNK - 1) / SCAN_CHUNK;
    const int block = 256;

    auto align_up = [](size_t x) { return (x + 255) & ~(size_t)255; };
    // rank-path layout
    size_t off_deg    = 0;
    size_t off_starts = off_deg    + align_up((size_t)Nn * 4);
    size_t off_bsum   = off_starts + align_up((size_t)Nn * 4);
    size_t off_boff   = off_bsum   + align_up((size_t)NB * 4);
    size_t off_adj    = off_boff   + align_up((size_t)NB * 4);
    size_t off_rank   = off_adj    + align_up((size_t)twoE * 4);
    size_t need_rank  = off_rank   + align_up((size_t)twoE * 4);
    // bump-path layout (rank slot becomes bump, smaller)
    size_t off_bump   = off_rank;
    size_t need_bump  = off_bump   + align_up((size_t)Nn * 4);

    if (ws_size < need_bump) {
        // low fallback: atomic scatter path
        hipMemsetAsync(out, 0, (size_t)ND * sizeof(float), stream);
        const long totalE = (long)E * D;
        edge_scatter_kernel<<<(int)((totalE + block - 1) / block), block, 0, stream>>>(
            z, ei, nf, out, E, D, totalE);
        finalize_kernel<<<(ND + block - 1) / block, block, 0, stream>>>(
            z, nf, out, scale, D, (long)ND);
        return;
    }

    char* w = (char*)d_ws;
    int* deg    = (int*)(w + off_deg);
    int* starts = (int*)(w + off_starts);
    int* bsum   = (int*)(w + off_bsum);
    int* boff   = (int*)(w + off_boff);
    int* adj    = (int*)(w + off_adj);

    hipMemsetAsync(deg, 0, (size_t)Nn * 4, stream);

    int gridE = (twoE + block - 1) / block;  // uncapped: 1 incidence per thread

    if (ws_size >= need_rank) {
        int* rank = (int*)(w + off_rank);
        hist_rank_kernel<<<gridE, block, 0, stream>>>(ei, deg, rank, twoE);
        scan_block_sums<<<NB, 256, 0, stream>>>(deg, bsum, Nn);
        scan_bsums<<<1, 256, 0, stream>>>(bsum, boff, NB);
        scan_chunks<<<NB, 256, 0, stream>>>(deg, boff, starts, Nn);
        scatter_rank_kernel<<<gridE, block, 0, stream>>>(ei, starts, rank, adj, E);
    } else {
        int* bump = (int*)(w + off_bump);
        hipMemsetAsync(bump, 0, (size_t)Nn * 4, stream);
        int* rankdummy = nullptr; (void)rankdummy;
        // hist without rank capture
        hist_rank_kernel<<<gridE, block, 0, stream>>>(ei, deg, bump /*scratch, rewritten below*/, twoE);
        // bump was clobbered as rank output only if twoE<=Nn — it is not; re-zero to be safe:
        hipMemsetAsync(bump, 0, (size_t)Nn * 4, stream);
        scan_block_sums<<<NB, 256, 0, stream>>>(deg, bsum, Nn);
        scan_bsums<<<1, 256, 0, stream>>>(bsum, boff, NB);
        scan_chunks<<<NB, 256, 0, stream>>>(deg, boff, starts, Nn);
        scatter_bump_kernel<<<gridE, block, 0, stream>>>(ei, starts, bump, adj, E);
    }

    const int C = D / 4;  // 12 float4 chunks per node
    long totalG = (long)Nn * C;
    int gridG = (int)((totalG + block - 1) / block);
    gather_finalize_v2<<<gridG, block, 0, stream>>>(
        (const float4*)z, nf, starts, deg, adj, (float4*)out, scale, Nn, C);
}